// Round 2
// baseline (447.410 us; speedup 1.0000x reference)
//
#include <hip/hip_runtime.h>
#include <hip/hip_bf16.h>

typedef __attribute__((ext_vector_type(8))) short short8;
typedef __attribute__((ext_vector_type(4))) float f32x4;

__device__ __forceinline__ unsigned short f2bf(float f) {
    __hip_bfloat16 h = __float2bfloat16(f);
    return *reinterpret_cast<unsigned short*>(&h);
}
__device__ __forceinline__ float bf2f(unsigned short u) {
    __hip_bfloat16 h = *reinterpret_cast<__hip_bfloat16*>(&u);
    return __bfloat162float(h);
}
__device__ __forceinline__ void hilo(float f, unsigned short& hi, unsigned short& lo) {
    hi = f2bf(f);
    lo = f2bf(f - bf2f(hi));
}

// ---------------- weight transpose + bf16 convert ----------------
// W [K][N] f32.  MODE 0: out[n*K + k] = bf16(W[k][n])
// MODE 1 (split3 for qkv): out row stride 3K: [n][k]=hi, [n][K+k]=lo, [n][2K+k]=hi
template<int MODE>
__global__ __launch_bounds__(256)
void transpose_w(const float* __restrict__ W, unsigned short* __restrict__ out, int K, int N) {
    __shared__ float tile[32][33];
    const int n0 = blockIdx.x * 32, k0 = blockIdx.y * 32;
    const int tid = threadIdx.x;
    const int r = tid >> 3, c4 = (tid & 7) << 2;
    float4 v = *reinterpret_cast<const float4*>(W + (size_t)(k0 + r) * N + n0 + c4);
    tile[r][c4 + 0] = v.x; tile[r][c4 + 1] = v.y;
    tile[r][c4 + 2] = v.z; tile[r][c4 + 3] = v.w;
    __syncthreads();
    const int n = n0 + r;
    if (MODE == 0) {
        ushort4 o;
        o.x = f2bf(tile[c4 + 0][r]); o.y = f2bf(tile[c4 + 1][r]);
        o.z = f2bf(tile[c4 + 2][r]); o.w = f2bf(tile[c4 + 3][r]);
        *reinterpret_cast<ushort4*>(out + (size_t)n * K + k0 + c4) = o;
    } else {
        ushort4 oh, ol;
        unsigned short hi, lo;
        hilo(tile[c4 + 0][r], hi, lo); oh.x = hi; ol.x = lo;
        hilo(tile[c4 + 1][r], hi, lo); oh.y = hi; ol.y = lo;
        hilo(tile[c4 + 2][r], hi, lo); oh.z = hi; ol.z = lo;
        hilo(tile[c4 + 3][r], hi, lo); oh.w = hi; ol.w = lo;
        size_t base = (size_t)n * 3 * K + k0 + c4;
        *reinterpret_cast<ushort4*>(out + base)         = oh;
        *reinterpret_cast<ushort4*>(out + base + K)     = ol;
        *reinterpret_cast<ushort4*>(out + base + 2 * K) = oh;
    }
}

// ---------------- LayerNorm ----------------
// MODE 0: out [row][1024] bf16.  MODE 1: out [row][3072]: hi, hi, lo (split3 A-layout)
template<int MODE>
__global__ __launch_bounds__(256)
void ln_kernel(const float* __restrict__ x, const float* __restrict__ gw,
               const float* __restrict__ bw, unsigned short* __restrict__ out) {
    const int row = blockIdx.x, tid = threadIdx.x;
    const float* xr = x + (size_t)row * 1024;
    float4 v = *reinterpret_cast<const float4*>(xr + tid * 4);
    float s = v.x + v.y + v.z + v.w;
    float sq = v.x * v.x + v.y * v.y + v.z * v.z + v.w * v.w;
    #pragma unroll
    for (int off = 1; off < 64; off <<= 1) {
        s  += __shfl_xor(s, off);
        sq += __shfl_xor(sq, off);
    }
    __shared__ float ps[4], pq[4];
    const int wave = tid >> 6;
    if ((tid & 63) == 0) { ps[wave] = s; pq[wave] = sq; }
    __syncthreads();
    s  = ps[0] + ps[1] + ps[2] + ps[3];
    sq = pq[0] + pq[1] + pq[2] + pq[3];
    const float mu = s * (1.0f / 1024.0f);
    const float var = sq * (1.0f / 1024.0f) - mu * mu;
    const float rs = rsqrtf(var + 1e-5f);
    float4 gv = *reinterpret_cast<const float4*>(gw + tid * 4);
    float4 bv = *reinterpret_cast<const float4*>(bw + tid * 4);
    float y[4];
    y[0] = (v.x - mu) * rs * gv.x + bv.x;
    y[1] = (v.y - mu) * rs * gv.y + bv.y;
    y[2] = (v.z - mu) * rs * gv.z + bv.z;
    y[3] = (v.w - mu) * rs * gv.w + bv.w;
    if (MODE == 0) {
        ushort4 o;
        o.x = f2bf(y[0]); o.y = f2bf(y[1]); o.z = f2bf(y[2]); o.w = f2bf(y[3]);
        *reinterpret_cast<ushort4*>(out + (size_t)row * 1024 + tid * 4) = o;
    } else {
        ushort4 oh, ol;
        unsigned short hi, lo;
        hilo(y[0], hi, lo); oh.x = hi; ol.x = lo;
        hilo(y[1], hi, lo); oh.y = hi; ol.y = lo;
        hilo(y[2], hi, lo); oh.z = hi; ol.z = lo;
        hilo(y[3], hi, lo); oh.w = hi; ol.w = lo;
        size_t base = (size_t)row * 3072 + tid * 4;
        *reinterpret_cast<ushort4*>(out + base)        = oh;
        *reinterpret_cast<ushort4*>(out + base + 1024) = oh;
        *reinterpret_cast<ushort4*>(out + base + 2048) = ol;
    }
}

// ---------------- GEMM: C = A @ B^T-input + bias (+epilogue) ----------------
// A [M][K] bf16 row-major, Bt [N][K] bf16 row-major. 128x128 tile, BK=32, 4 waves.
// EPI 0: f32 = acc+bias ; EPI 1: f32 = acc+bias+resid ; EPI 2: bf16 = gelu(acc+bias)
template<int EPI>
__global__ __launch_bounds__(256)
void gemm_bt(const unsigned short* __restrict__ A, const unsigned short* __restrict__ Bt,
             const float* __restrict__ bias, const float* resid,
             void* Cout, int M, int N, int K) {
    __shared__ unsigned short As[128][56];
    __shared__ unsigned short Bs[128][56];
    const int tid = threadIdx.x;
    const int wave = tid >> 6, lane = tid & 63;
    const int bm = blockIdx.y << 7, bn = blockIdx.x << 7;
    const int wr = (wave >> 1) << 6, wc = (wave & 1) << 6;
    const int fr = lane & 15, g8 = (lane >> 4) << 3, fq = (lane >> 4) << 2;
    const int sr = tid >> 2, sc = (tid & 3) << 3;
    const unsigned short* Ar0 = A + (size_t)(bm + sr) * K + sc;
    const unsigned short* Ar1 = Ar0 + (size_t)64 * K;
    const unsigned short* Br0 = Bt + (size_t)(bn + sr) * K + sc;
    const unsigned short* Br1 = Br0 + (size_t)64 * K;

    f32x4 acc[4][4];
    #pragma unroll
    for (int m = 0; m < 4; ++m)
        #pragma unroll
        for (int n = 0; n < 4; ++n)
            #pragma unroll
            for (int r = 0; r < 4; ++r) acc[m][n][r] = 0.0f;

    for (int k0 = 0; k0 < K; k0 += 32) {
        __syncthreads();
        *reinterpret_cast<short8*>(&As[sr][sc])      = *reinterpret_cast<const short8*>(Ar0 + k0);
        *reinterpret_cast<short8*>(&As[sr + 64][sc]) = *reinterpret_cast<const short8*>(Ar1 + k0);
        *reinterpret_cast<short8*>(&Bs[sr][sc])      = *reinterpret_cast<const short8*>(Br0 + k0);
        *reinterpret_cast<short8*>(&Bs[sr + 64][sc]) = *reinterpret_cast<const short8*>(Br1 + k0);
        __syncthreads();
        short8 af[4], bfv[4];
        #pragma unroll
        for (int m = 0; m < 4; ++m)
            af[m] = *reinterpret_cast<const short8*>(&As[wr + m * 16 + fr][g8]);
        #pragma unroll
        for (int n = 0; n < 4; ++n)
            bfv[n] = *reinterpret_cast<const short8*>(&Bs[wc + n * 16 + fr][g8]);
        #pragma unroll
        for (int m = 0; m < 4; ++m)
            #pragma unroll
            for (int n = 0; n < 4; ++n)
                acc[m][n] = __builtin_amdgcn_mfma_f32_16x16x32_bf16(af[m], bfv[n], acc[m][n], 0, 0, 0);
    }

    #pragma unroll
    for (int n = 0; n < 4; ++n) {
        const int col = bn + wc + n * 16 + fr;
        const float bc = bias[col];
        #pragma unroll
        for (int m = 0; m < 4; ++m) {
            #pragma unroll
            for (int r = 0; r < 4; ++r) {
                const int row = bm + wr + m * 16 + fq + r;
                const size_t idx = (size_t)row * N + col;
                float v = acc[m][n][r] + bc;
                if (EPI == 0) {
                    reinterpret_cast<float*>(Cout)[idx] = v;
                } else if (EPI == 1) {
                    reinterpret_cast<float*>(Cout)[idx] = v + resid[idx];
                } else {
                    float ge = 0.5f * v * (1.0f + erff(v * 0.70710678118654752f));
                    reinterpret_cast<unsigned short*>(Cout)[idx] = f2bf(ge);
                }
            }
        }
    }
}

// ---------------- Flash attention ----------------
// qkv f32 [4096][3072] (row: [q(16*64) | k(16*64) | v(16*64)]), ctx bf16 [4096][1024]
// scores = (q . k) * 8  (reference multiplies by sqrt(dk)!)
// Split precision QK^T: S = qhi.khi + qhi.klo + qlo.khi
__global__ __launch_bounds__(256)
void attn_kernel(const float* __restrict__ qkv, unsigned short* __restrict__ ctx) {
    __shared__ unsigned short Khi[64][72];
    __shared__ unsigned short Klo[64][72];
    __shared__ unsigned short Vt[64][72];
    __shared__ unsigned short Plds[4][16][72];
    const int qt = blockIdx.x;          // 16 q-tiles of 64 rows
    const int bh = blockIdx.y;          // b*16 + h
    const int b = bh >> 4, h = bh & 15;
    const int tid = threadIdx.x;
    const int wave = tid >> 6, lane = tid & 63;
    const int fr = lane & 15, g8 = (lane >> 4) << 3, fq = (lane >> 4) << 2;

    // Q fragments in registers (hi/lo, 2 k-steps over dk=64)
    const int qrow = qt * 64 + wave * 16 + fr;
    const float* qp = qkv + ((size_t)(b * 1024 + qrow)) * 3072 + h * 64;
    short8 qhi[2], qlo[2];
    #pragma unroll
    for (int s_ = 0; s_ < 2; ++s_) {
        #pragma unroll
        for (int j = 0; j < 8; ++j) {
            float f = qp[s_ * 32 + g8 + j];
            unsigned short hi = f2bf(f);
            qhi[s_][j] = (short)hi;
            qlo[s_][j] = (short)f2bf(f - bf2f(hi));
        }
    }

    float mrun[4], lrun[4];
    f32x4 cacc[4];
    #pragma unroll
    for (int r = 0; r < 4; ++r) { mrun[r] = -3.0e38f; lrun[r] = 0.0f; }
    #pragma unroll
    for (int nd = 0; nd < 4; ++nd)
        #pragma unroll
        for (int r = 0; r < 4; ++r) cacc[nd][r] = 0.0f;

    const int skey = tid >> 2, sd = (tid & 3) << 4;
    const float* kvbase = qkv + ((size_t)(b * 1024 + skey)) * 3072 + h * 64 + sd;

    for (int kt = 0; kt < 16; ++kt) {
        __syncthreads();
        // stage K (hi/lo) and V^T for keys kt*64..+63
        const float* kp = kvbase + (size_t)kt * 64 * 3072;
        #pragma unroll
        for (int j = 0; j < 16; j += 4) {
            float4 kv4 = *reinterpret_cast<const float4*>(kp + 1024 + j);
            float4 vv4 = *reinterpret_cast<const float4*>(kp + 2048 + j);
            float ks[4] = {kv4.x, kv4.y, kv4.z, kv4.w};
            float vs[4] = {vv4.x, vv4.y, vv4.z, vv4.w};
            #pragma unroll
            for (int c = 0; c < 4; ++c) {
                unsigned short hi = f2bf(ks[c]);
                Khi[skey][sd + j + c] = hi;
                Klo[skey][sd + j + c] = f2bf(ks[c] - bf2f(hi));
                Vt[sd + j + c][skey] = f2bf(vs[c]);
            }
        }
        __syncthreads();

        short8 kh[2][4], kl[2][4];
        #pragma unroll
        for (int s_ = 0; s_ < 2; ++s_)
            #pragma unroll
            for (int n = 0; n < 4; ++n) {
                kh[s_][n] = *reinterpret_cast<const short8*>(&Khi[n * 16 + fr][s_ * 32 + g8]);
                kl[s_][n] = *reinterpret_cast<const short8*>(&Klo[n * 16 + fr][s_ * 32 + g8]);
            }
        f32x4 S[4];
        #pragma unroll
        for (int n = 0; n < 4; ++n)
            #pragma unroll
            for (int r = 0; r < 4; ++r) S[n][r] = 0.0f;
        #pragma unroll
        for (int s_ = 0; s_ < 2; ++s_)
            #pragma unroll
            for (int n = 0; n < 4; ++n)
                S[n] = __builtin_amdgcn_mfma_f32_16x16x32_bf16(qhi[s_], kh[s_][n], S[n], 0, 0, 0);
        #pragma unroll
        for (int s_ = 0; s_ < 2; ++s_)
            #pragma unroll
            for (int n = 0; n < 4; ++n)
                S[n] = __builtin_amdgcn_mfma_f32_16x16x32_bf16(qhi[s_], kl[s_][n], S[n], 0, 0, 0);
        #pragma unroll
        for (int s_ = 0; s_ < 2; ++s_)
            #pragma unroll
            for (int n = 0; n < 4; ++n)
                S[n] = __builtin_amdgcn_mfma_f32_16x16x32_bf16(qlo[s_], kh[s_][n], S[n], 0, 0, 0);

        // online softmax: lane holds rows fq+r, cols n*16 + fr (per D-layout)
        float mt[4];
        #pragma unroll
        for (int r = 0; r < 4; ++r)
            mt[r] = fmaxf(fmaxf(S[0][r], S[1][r]), fmaxf(S[2][r], S[3][r])) * 8.0f;
        #pragma unroll
        for (int r = 0; r < 4; ++r) {
            mt[r] = fmaxf(mt[r], __shfl_xor(mt[r], 1));
            mt[r] = fmaxf(mt[r], __shfl_xor(mt[r], 2));
            mt[r] = fmaxf(mt[r], __shfl_xor(mt[r], 4));
            mt[r] = fmaxf(mt[r], __shfl_xor(mt[r], 8));
        }
        float P[4][4], rsum[4];
        #pragma unroll
        for (int r = 0; r < 4; ++r) {
            float mnew = fmaxf(mrun[r], mt[r]);
            float sf = __expf(mrun[r] - mnew);
            mrun[r] = mnew;
            rsum[r] = 0.0f;
            #pragma unroll
            for (int n = 0; n < 4; ++n) {
                float p = __expf(S[n][r] * 8.0f - mnew);
                P[n][r] = p;
                rsum[r] += p;
            }
            lrun[r] *= sf;
            #pragma unroll
            for (int nd = 0; nd < 4; ++nd) cacc[nd][r] *= sf;
        }
        #pragma unroll
        for (int r = 0; r < 4; ++r) {
            rsum[r] += __shfl_xor(rsum[r], 1);
            rsum[r] += __shfl_xor(rsum[r], 2);
            rsum[r] += __shfl_xor(rsum[r], 4);
            rsum[r] += __shfl_xor(rsum[r], 8);
            lrun[r] += rsum[r];
        }
        // P -> LDS (re-fragment for PV A-operand)
        #pragma unroll
        for (int n = 0; n < 4; ++n)
            #pragma unroll
            for (int r = 0; r < 4; ++r)
                Plds[wave][fq + r][n * 16 + fr] = f2bf(P[n][r]);
        __syncthreads();
        // PV: ctx += P @ V
        #pragma unroll
        for (int s_ = 0; s_ < 2; ++s_) {
            short8 pa = *reinterpret_cast<const short8*>(&Plds[wave][fr][s_ * 32 + g8]);
            #pragma unroll
            for (int nd = 0; nd < 4; ++nd) {
                short8 vb = *reinterpret_cast<const short8*>(&Vt[nd * 16 + fr][s_ * 32 + g8]);
                cacc[nd] = __builtin_amdgcn_mfma_f32_16x16x32_bf16(pa, vb, cacc[nd], 0, 0, 0);
            }
        }
    }
    // epilogue: ctx = cacc / l
    #pragma unroll
    for (int r = 0; r < 4; ++r) {
        const float inv = 1.0f / lrun[r];
        const int row = qt * 64 + wave * 16 + fq + r;
        unsigned short* cp = ctx + ((size_t)(b * 1024 + row)) * 1024 + h * 64;
        #pragma unroll
        for (int nd = 0; nd < 4; ++nd)
            cp[nd * 16 + fr] = f2bf(cacc[nd][r] * inv);
    }
}

// ---------------- launch ----------------
extern "C" void kernel_launch(void* const* d_in, const int* in_sizes, int n_in,
                              void* d_out, int out_size, void* d_ws, size_t ws_size,
                              hipStream_t stream) {
    const float* x      = (const float*)d_in[0];
    const float* norm_g = (const float*)d_in[1];
    const float* norm_b = (const float*)d_in[2];
    const float* w_qkv  = (const float*)d_in[3];
    const float* b_qkv  = (const float*)d_in[4];
    const float* w_proj = (const float*)d_in[5];
    const float* b_proj = (const float*)d_in[6];
    const float* w_fc1  = (const float*)d_in[7];
    const float* b_fc1  = (const float*)d_in[8];
    const float* w_fc2  = (const float*)d_in[9];
    const float* b_fc2  = (const float*)d_in[10];
    float* out = (float*)d_out;
    char* ws = (char*)d_ws;

    // workspace layout (~122 MB, with dead-buffer overlap in region G)
    size_t off = 0;
    unsigned short* wqkvT3 = (unsigned short*)(ws + off); off += (size_t)3072 * 3072 * 2;
    unsigned short* wprojT = (unsigned short*)(ws + off); off += (size_t)1024 * 1024 * 2;
    unsigned short* wfc1T  = (unsigned short*)(ws + off); off += (size_t)4096 * 1024 * 2;
    unsigned short* wfc2T  = (unsigned short*)(ws + off); off += (size_t)1024 * 4096 * 2;
    unsigned short* ctxb   = (unsigned short*)(ws + off); off += (size_t)4096 * 1024 * 2;
    char* G = ws + off;
    unsigned short* h3    = (unsigned short*)G;                     // [4096][3072], dead after qkv GEMM
    float*          qkvf  = (float*)(G + (size_t)25165824);         // [4096][3072] f32, dead after attn
    unsigned short* fc1o  = (unsigned short*)G;                     // [4096][4096], overlaps h3+qkv head
    unsigned short* h2    = (unsigned short*)(G + (size_t)33554432);// [4096][1024], overlaps qkv tail

    // weight prep
    transpose_w<1><<<dim3(96, 32),  256, 0, stream>>>(w_qkv,  wqkvT3, 1024, 3072);
    transpose_w<0><<<dim3(32, 32),  256, 0, stream>>>(w_proj, wprojT, 1024, 1024);
    transpose_w<0><<<dim3(128, 32), 256, 0, stream>>>(w_fc1,  wfc1T,  1024, 4096);
    transpose_w<0><<<dim3(32, 128), 256, 0, stream>>>(w_fc2,  wfc2T,  4096, 1024);

    // h = LN(x) (split3) ; qkv = h @ w_qkv + b  (split-precision via K'=3072)
    ln_kernel<1><<<4096, 256, 0, stream>>>(x, norm_g, norm_b, h3);
    gemm_bt<0><<<dim3(24, 32), 256, 0, stream>>>(h3, wqkvT3, b_qkv, nullptr, qkvf, 4096, 3072, 3072);

    // attention -> ctx (bf16)
    attn_kernel<<<dim3(16, 64), 256, 0, stream>>>(qkvf, ctxb);

    // x1 = x + ctx @ w_proj + b   (x1 lives in d_out)
    gemm_bt<1><<<dim3(8, 32), 256, 0, stream>>>(ctxb, wprojT, b_proj, x, out, 4096, 1024, 1024);

    // h2 = LN(x1) ; fc1 = gelu(h2 @ w_fc1 + b) ; out = x1 + fc1 @ w_fc2 + b (in-place)
    ln_kernel<0><<<4096, 256, 0, stream>>>(out, norm_g, norm_b, h2);
    gemm_bt<2><<<dim3(32, 32), 256, 0, stream>>>(h2, wfc1T, b_fc1, nullptr, fc1o, 4096, 4096, 1024);
    gemm_bt<1><<<dim3(8, 32), 256, 0, stream>>>(fc1o, wfc2T, b_fc2, out, out, 4096, 1024, 4096);
}

// Round 3
// 446.567 us; speedup vs baseline: 1.0019x; 1.0019x over previous
//
#include <hip/hip_runtime.h>
#include <hip/hip_bf16.h>

typedef __attribute__((ext_vector_type(8))) short short8;
typedef __attribute__((ext_vector_type(4))) float f32x4;

__device__ __forceinline__ unsigned short f2bf(float f) {
    __hip_bfloat16 h = __float2bfloat16(f);
    return *reinterpret_cast<unsigned short*>(&h);
}
__device__ __forceinline__ float bf2f(unsigned short u) {
    __hip_bfloat16 h = *reinterpret_cast<__hip_bfloat16*>(&u);
    return __bfloat162float(h);
}
__device__ __forceinline__ void hilo(float f, unsigned short& hi, unsigned short& lo) {
    hi = f2bf(f);
    lo = f2bf(f - bf2f(hi));
}

// ---------------- weight transpose + bf16 convert ----------------
// W [K][N] f32.  MODE 0: out[n*K + k] = bf16(W[k][n])
// MODE 1 (split3 for qkv): out row stride 3K: [n][k]=hi, [n][K+k]=lo, [n][2K+k]=hi
template<int MODE>
__global__ __launch_bounds__(256)
void transpose_w(const float* __restrict__ W, unsigned short* __restrict__ out, int K, int N) {
    __shared__ float tile[32][33];
    const int n0 = blockIdx.x * 32, k0 = blockIdx.y * 32;
    const int tid = threadIdx.x;
    const int r = tid >> 3, c4 = (tid & 7) << 2;
    float4 v = *reinterpret_cast<const float4*>(W + (size_t)(k0 + r) * N + n0 + c4);
    tile[r][c4 + 0] = v.x; tile[r][c4 + 1] = v.y;
    tile[r][c4 + 2] = v.z; tile[r][c4 + 3] = v.w;
    __syncthreads();
    const int n = n0 + r;
    if (MODE == 0) {
        ushort4 o;
        o.x = f2bf(tile[c4 + 0][r]); o.y = f2bf(tile[c4 + 1][r]);
        o.z = f2bf(tile[c4 + 2][r]); o.w = f2bf(tile[c4 + 3][r]);
        *reinterpret_cast<ushort4*>(out + (size_t)n * K + k0 + c4) = o;
    } else {
        ushort4 oh, ol;
        unsigned short hi, lo;
        hilo(tile[c4 + 0][r], hi, lo); oh.x = hi; ol.x = lo;
        hilo(tile[c4 + 1][r], hi, lo); oh.y = hi; ol.y = lo;
        hilo(tile[c4 + 2][r], hi, lo); oh.z = hi; ol.z = lo;
        hilo(tile[c4 + 3][r], hi, lo); oh.w = hi; ol.w = lo;
        size_t base = (size_t)n * 3 * K + k0 + c4;
        *reinterpret_cast<ushort4*>(out + base)         = oh;
        *reinterpret_cast<ushort4*>(out + base + K)     = ol;
        *reinterpret_cast<ushort4*>(out + base + 2 * K) = oh;
    }
}

// ---------------- LayerNorm ----------------
// MODE 0: out [row][1024] bf16.  MODE 1: out [row][3072]: hi, hi, lo (split3 A-layout)
template<int MODE>
__global__ __launch_bounds__(256)
void ln_kernel(const float* __restrict__ x, const float* __restrict__ gw,
               const float* __restrict__ bw, unsigned short* __restrict__ out) {
    const int row = blockIdx.x, tid = threadIdx.x;
    const float* xr = x + (size_t)row * 1024;
    float4 v = *reinterpret_cast<const float4*>(xr + tid * 4);
    float s = v.x + v.y + v.z + v.w;
    float sq = v.x * v.x + v.y * v.y + v.z * v.z + v.w * v.w;
    #pragma unroll
    for (int off = 1; off < 64; off <<= 1) {
        s  += __shfl_xor(s, off);
        sq += __shfl_xor(sq, off);
    }
    __shared__ float ps[4], pq[4];
    const int wave = tid >> 6;
    if ((tid & 63) == 0) { ps[wave] = s; pq[wave] = sq; }
    __syncthreads();
    s  = ps[0] + ps[1] + ps[2] + ps[3];
    sq = pq[0] + pq[1] + pq[2] + pq[3];
    const float mu = s * (1.0f / 1024.0f);
    const float var = sq * (1.0f / 1024.0f) - mu * mu;
    const float rs = rsqrtf(var + 1e-5f);
    float4 gv = *reinterpret_cast<const float4*>(gw + tid * 4);
    float4 bv = *reinterpret_cast<const float4*>(bw + tid * 4);
    float y[4];
    y[0] = (v.x - mu) * rs * gv.x + bv.x;
    y[1] = (v.y - mu) * rs * gv.y + bv.y;
    y[2] = (v.z - mu) * rs * gv.z + bv.z;
    y[3] = (v.w - mu) * rs * gv.w + bv.w;
    if (MODE == 0) {
        ushort4 o;
        o.x = f2bf(y[0]); o.y = f2bf(y[1]); o.z = f2bf(y[2]); o.w = f2bf(y[3]);
        *reinterpret_cast<ushort4*>(out + (size_t)row * 1024 + tid * 4) = o;
    } else {
        ushort4 oh, ol;
        unsigned short hi, lo;
        hilo(y[0], hi, lo); oh.x = hi; ol.x = lo;
        hilo(y[1], hi, lo); oh.y = hi; ol.y = lo;
        hilo(y[2], hi, lo); oh.z = hi; ol.z = lo;
        hilo(y[3], hi, lo); oh.w = hi; ol.w = lo;
        size_t base = (size_t)row * 3072 + tid * 4;
        *reinterpret_cast<ushort4*>(out + base)        = oh;
        *reinterpret_cast<ushort4*>(out + base + 1024) = oh;
        *reinterpret_cast<ushort4*>(out + base + 2048) = ol;
    }
}

// ---------------- GEMM: C = A @ B^T-input + bias (+epilogue) ----------------
// A [M][K] bf16 row-major, Bt [N][K] bf16 row-major. 128x128 tile, BK=32, 4 waves.
// EPI 0: f32 = acc+bias ; EPI 1: f32 = acc+bias+resid ; EPI 2: bf16 = gelu(acc+bias)
template<int EPI>
__global__ __launch_bounds__(256)
void gemm_bt(const unsigned short* __restrict__ A, const unsigned short* __restrict__ Bt,
             const float* __restrict__ bias, const float* resid,
             void* Cout, int M, int N, int K) {
    __shared__ unsigned short As[128][56];
    __shared__ unsigned short Bs[128][56];
    const int tid = threadIdx.x;
    const int wave = tid >> 6, lane = tid & 63;
    const int bm = blockIdx.y << 7, bn = blockIdx.x << 7;
    const int wr = (wave >> 1) << 6, wc = (wave & 1) << 6;
    const int fr = lane & 15, g8 = (lane >> 4) << 3, fq = (lane >> 4) << 2;
    const int sr = tid >> 2, sc = (tid & 3) << 3;
    const unsigned short* Ar0 = A + (size_t)(bm + sr) * K + sc;
    const unsigned short* Ar1 = Ar0 + (size_t)64 * K;
    const unsigned short* Br0 = Bt + (size_t)(bn + sr) * K + sc;
    const unsigned short* Br1 = Br0 + (size_t)64 * K;

    f32x4 acc[4][4];
    #pragma unroll
    for (int m = 0; m < 4; ++m)
        #pragma unroll
        for (int n = 0; n < 4; ++n)
            #pragma unroll
            for (int r = 0; r < 4; ++r) acc[m][n][r] = 0.0f;

    for (int k0 = 0; k0 < K; k0 += 32) {
        __syncthreads();
        *reinterpret_cast<short8*>(&As[sr][sc])      = *reinterpret_cast<const short8*>(Ar0 + k0);
        *reinterpret_cast<short8*>(&As[sr + 64][sc]) = *reinterpret_cast<const short8*>(Ar1 + k0);
        *reinterpret_cast<short8*>(&Bs[sr][sc])      = *reinterpret_cast<const short8*>(Br0 + k0);
        *reinterpret_cast<short8*>(&Bs[sr + 64][sc]) = *reinterpret_cast<const short8*>(Br1 + k0);
        __syncthreads();
        short8 af[4], bfv[4];
        #pragma unroll
        for (int m = 0; m < 4; ++m)
            af[m] = *reinterpret_cast<const short8*>(&As[wr + m * 16 + fr][g8]);
        #pragma unroll
        for (int n = 0; n < 4; ++n)
            bfv[n] = *reinterpret_cast<const short8*>(&Bs[wc + n * 16 + fr][g8]);
        #pragma unroll
        for (int m = 0; m < 4; ++m)
            #pragma unroll
            for (int n = 0; n < 4; ++n)
                acc[m][n] = __builtin_amdgcn_mfma_f32_16x16x32_bf16(af[m], bfv[n], acc[m][n], 0, 0, 0);
    }

    #pragma unroll
    for (int n = 0; n < 4; ++n) {
        const int col = bn + wc + n * 16 + fr;
        const float bc = bias[col];
        #pragma unroll
        for (int m = 0; m < 4; ++m) {
            #pragma unroll
            for (int r = 0; r < 4; ++r) {
                const int row = bm + wr + m * 16 + fq + r;
                const size_t idx = (size_t)row * N + col;
                float v = acc[m][n][r] + bc;
                if (EPI == 0) {
                    reinterpret_cast<float*>(Cout)[idx] = v;
                } else if (EPI == 1) {
                    reinterpret_cast<float*>(Cout)[idx] = v + resid[idx];
                } else {
                    float ge = 0.5f * v * (1.0f + erff(v * 0.70710678118654752f));
                    reinterpret_cast<unsigned short*>(Cout)[idx] = f2bf(ge);
                }
            }
        }
    }
}

// ---------------- Flash attention ----------------
// qkv f32 [4096][3072] (row: [q(16*64) | k(16*64) | v(16*64)]), ctx bf16 [4096][1024]
// scores = (q . k) * 8  (reference multiplies by sqrt(dk)!)
// Split precision QK^T: S = qhi.khi + qhi.klo + qlo.khi
__global__ __launch_bounds__(256)
void attn_kernel(const float* __restrict__ qkv, unsigned short* __restrict__ ctx) {
    __shared__ unsigned short Khi[64][72];
    __shared__ unsigned short Klo[64][72];
    __shared__ unsigned short Vt[64][72];
    __shared__ unsigned short Plds[4][16][72];
    const int qt = blockIdx.x;          // 16 q-tiles of 64 rows
    const int bh = blockIdx.y;          // b*16 + h
    const int b = bh >> 4, h = bh & 15;
    const int tid = threadIdx.x;
    const int wave = tid >> 6, lane = tid & 63;
    const int fr = lane & 15, g8 = (lane >> 4) << 3, fq = (lane >> 4) << 2;

    // Q fragments in registers (hi/lo, 2 k-steps over dk=64)
    const int qrow = qt * 64 + wave * 16 + fr;
    const float* qp = qkv + ((size_t)(b * 1024 + qrow)) * 3072 + h * 64;
    short8 qhi[2], qlo[2];
    #pragma unroll
    for (int s_ = 0; s_ < 2; ++s_) {
        #pragma unroll
        for (int j = 0; j < 8; ++j) {
            float f = qp[s_ * 32 + g8 + j];
            unsigned short hi = f2bf(f);
            qhi[s_][j] = (short)hi;
            qlo[s_][j] = (short)f2bf(f - bf2f(hi));
        }
    }

    float mrun[4], lrun[4];
    f32x4 cacc[4];
    #pragma unroll
    for (int r = 0; r < 4; ++r) { mrun[r] = -3.0e38f; lrun[r] = 0.0f; }
    #pragma unroll
    for (int nd = 0; nd < 4; ++nd)
        #pragma unroll
        for (int r = 0; r < 4; ++r) cacc[nd][r] = 0.0f;

    const int skey = tid >> 2, sd = (tid & 3) << 4;
    const float* kvbase = qkv + ((size_t)(b * 1024 + skey)) * 3072 + h * 64 + sd;

    for (int kt = 0; kt < 16; ++kt) {
        __syncthreads();
        // stage K (hi/lo) and V^T for keys kt*64..+63
        const float* kp = kvbase + (size_t)kt * 64 * 3072;
        #pragma unroll
        for (int j = 0; j < 16; j += 4) {
            float4 kv4 = *reinterpret_cast<const float4*>(kp + 1024 + j);
            float4 vv4 = *reinterpret_cast<const float4*>(kp + 2048 + j);
            float ks[4] = {kv4.x, kv4.y, kv4.z, kv4.w};
            float vs[4] = {vv4.x, vv4.y, vv4.z, vv4.w};
            #pragma unroll
            for (int c = 0; c < 4; ++c) {
                unsigned short hi = f2bf(ks[c]);
                Khi[skey][sd + j + c] = hi;
                Klo[skey][sd + j + c] = f2bf(ks[c] - bf2f(hi));
                Vt[sd + j + c][skey] = f2bf(vs[c]);
            }
        }
        __syncthreads();

        short8 kh[2][4], kl[2][4];
        #pragma unroll
        for (int s_ = 0; s_ < 2; ++s_)
            #pragma unroll
            for (int n = 0; n < 4; ++n) {
                kh[s_][n] = *reinterpret_cast<const short8*>(&Khi[n * 16 + fr][s_ * 32 + g8]);
                kl[s_][n] = *reinterpret_cast<const short8*>(&Klo[n * 16 + fr][s_ * 32 + g8]);
            }
        f32x4 S[4];
        #pragma unroll
        for (int n = 0; n < 4; ++n)
            #pragma unroll
            for (int r = 0; r < 4; ++r) S[n][r] = 0.0f;
        #pragma unroll
        for (int s_ = 0; s_ < 2; ++s_)
            #pragma unroll
            for (int n = 0; n < 4; ++n)
                S[n] = __builtin_amdgcn_mfma_f32_16x16x32_bf16(qhi[s_], kh[s_][n], S[n], 0, 0, 0);
        #pragma unroll
        for (int s_ = 0; s_ < 2; ++s_)
            #pragma unroll
            for (int n = 0; n < 4; ++n)
                S[n] = __builtin_amdgcn_mfma_f32_16x16x32_bf16(qhi[s_], kl[s_][n], S[n], 0, 0, 0);
        #pragma unroll
        for (int s_ = 0; s_ < 2; ++s_)
            #pragma unroll
            for (int n = 0; n < 4; ++n)
                S[n] = __builtin_amdgcn_mfma_f32_16x16x32_bf16(qlo[s_], kh[s_][n], S[n], 0, 0, 0);

        // online softmax: lane holds rows fq+r, cols n*16 + fr (per D-layout)
        float mt[4];
        #pragma unroll
        for (int r = 0; r < 4; ++r)
            mt[r] = fmaxf(fmaxf(S[0][r], S[1][r]), fmaxf(S[2][r], S[3][r])) * 8.0f;
        #pragma unroll
        for (int r = 0; r < 4; ++r) {
            mt[r] = fmaxf(mt[r], __shfl_xor(mt[r], 1));
            mt[r] = fmaxf(mt[r], __shfl_xor(mt[r], 2));
            mt[r] = fmaxf(mt[r], __shfl_xor(mt[r], 4));
            mt[r] = fmaxf(mt[r], __shfl_xor(mt[r], 8));
        }
        float P[4][4], rsum[4];
        #pragma unroll
        for (int r = 0; r < 4; ++r) {
            float mnew = fmaxf(mrun[r], mt[r]);
            float sf = __expf(mrun[r] - mnew);
            mrun[r] = mnew;
            rsum[r] = 0.0f;
            #pragma unroll
            for (int n = 0; n < 4; ++n) {
                float p = __expf(S[n][r] * 8.0f - mnew);
                P[n][r] = p;
                rsum[r] += p;
            }
            lrun[r] *= sf;
            #pragma unroll
            for (int nd = 0; nd < 4; ++nd) cacc[nd][r] *= sf;
        }
        #pragma unroll
        for (int r = 0; r < 4; ++r) {
            rsum[r] += __shfl_xor(rsum[r], 1);
            rsum[r] += __shfl_xor(rsum[r], 2);
            rsum[r] += __shfl_xor(rsum[r], 4);
            rsum[r] += __shfl_xor(rsum[r], 8);
            lrun[r] += rsum[r];
        }
        // P -> LDS (re-fragment for PV A-operand)
        #pragma unroll
        for (int n = 0; n < 4; ++n)
            #pragma unroll
            for (int r = 0; r < 4; ++r)
                Plds[wave][fq + r][n * 16 + fr] = f2bf(P[n][r]);
        __syncthreads();
        // PV: ctx += P @ V
        #pragma unroll
        for (int s_ = 0; s_ < 2; ++s_) {
            short8 pa = *reinterpret_cast<const short8*>(&Plds[wave][fr][s_ * 32 + g8]);
            #pragma unroll
            for (int nd = 0; nd < 4; ++nd) {
                short8 vb = *reinterpret_cast<const short8*>(&Vt[nd * 16 + fr][s_ * 32 + g8]);
                cacc[nd] = __builtin_amdgcn_mfma_f32_16x16x32_bf16(pa, vb, cacc[nd], 0, 0, 0);
            }
        }
    }
    // epilogue: ctx = cacc / l
    #pragma unroll
    for (int r = 0; r < 4; ++r) {
        const float inv = 1.0f / lrun[r];
        const int row = qt * 64 + wave * 16 + fq + r;
        unsigned short* cp = ctx + ((size_t)(b * 1024 + row)) * 1024 + h * 64;
        #pragma unroll
        for (int nd = 0; nd < 4; ++nd)
            cp[nd * 16 + fr] = f2bf(cacc[nd][r] * inv);
    }
}

// ---------------- launch ----------------
extern "C" void kernel_launch(void* const* d_in, const int* in_sizes, int n_in,
                              void* d_out, int out_size, void* d_ws, size_t ws_size,
                              hipStream_t stream) {
    const float* x      = (const float*)d_in[0];
    const float* norm_g = (const float*)d_in[1];
    const float* norm_b = (const float*)d_in[2];
    const float* w_qkv  = (const float*)d_in[3];
    const float* b_qkv  = (const float*)d_in[4];
    const float* w_proj = (const float*)d_in[5];
    const float* b_proj = (const float*)d_in[6];
    const float* w_fc1  = (const float*)d_in[7];
    const float* b_fc1  = (const float*)d_in[8];
    const float* w_fc2  = (const float*)d_in[9];
    const float* b_fc2  = (const float*)d_in[10];
    float* out = (float*)d_out;
    char* ws = (char*)d_ws;

    // workspace layout (~122 MB, with dead-buffer overlap in region G)
    size_t off = 0;
    unsigned short* wqkvT3 = (unsigned short*)(ws + off); off += (size_t)3072 * 3072 * 2;
    unsigned short* wprojT = (unsigned short*)(ws + off); off += (size_t)1024 * 1024 * 2;
    unsigned short* wfc1T  = (unsigned short*)(ws + off); off += (size_t)4096 * 1024 * 2;
    unsigned short* wfc2T  = (unsigned short*)(ws + off); off += (size_t)1024 * 4096 * 2;
    unsigned short* ctxb   = (unsigned short*)(ws + off); off += (size_t)4096 * 1024 * 2;
    char* G = ws + off;
    unsigned short* h3    = (unsigned short*)G;                     // [4096][3072], dead after qkv GEMM
    float*          qkvf  = (float*)(G + (size_t)25165824);         // [4096][3072] f32, dead after attn
    unsigned short* fc1o  = (unsigned short*)G;                     // [4096][4096], overlaps h3+qkv head
    unsigned short* h2    = (unsigned short*)(G + (size_t)33554432);// [4096][1024], overlaps qkv tail

    // weight prep
    transpose_w<1><<<dim3(96, 32),  256, 0, stream>>>(w_qkv,  wqkvT3, 1024, 3072);
    transpose_w<0><<<dim3(32, 32),  256, 0, stream>>>(w_proj, wprojT, 1024, 1024);
    transpose_w<0><<<dim3(128, 32), 256, 0, stream>>>(w_fc1,  wfc1T,  1024, 4096);
    transpose_w<0><<<dim3(32, 128), 256, 0, stream>>>(w_fc2,  wfc2T,  4096, 1024);

    // h = LN(x) (split3) ; qkv = h @ w_qkv + b  (split-precision via K'=3072)
    ln_kernel<1><<<4096, 256, 0, stream>>>(x, norm_g, norm_b, h3);
    gemm_bt<0><<<dim3(24, 32), 256, 0, stream>>>(h3, wqkvT3, b_qkv, nullptr, qkvf, 4096, 3072, 3072);

    // attention -> ctx (bf16)
    attn_kernel<<<dim3(16, 64), 256, 0, stream>>>(qkvf, ctxb);

    // x1 = x + ctx @ w_proj + b   (x1 lives in d_out)
    gemm_bt<1><<<dim3(8, 32), 256, 0, stream>>>(ctxb, wprojT, b_proj, x, out, 4096, 1024, 1024);

    // h2 = LN(x1) ; fc1 = gelu(h2 @ w_fc1 + b) ; out = x1 + fc1 @ w_fc2 + b (in-place)
    ln_kernel<0><<<4096, 256, 0, stream>>>(out, norm_g, norm_b, h2);
    gemm_bt<2><<<dim3(32, 32), 256, 0, stream>>>(h2, wfc1T, b_fc1, nullptr, fc1o, 4096, 4096, 1024);
    gemm_bt<1><<<dim3(8, 32), 256, 0, stream>>>(fc1o, wfc2T, b_fc2, out, out, 4096, 1024, 4096);
}